// Round 1
// baseline (162.833 us; speedup 1.0000x reference)
//
#include <hip/hip_runtime.h>
#include <math.h>

static constexpr int K = 512;
static constexpr int D = 256;
static constexpr float ALPHA = 0.99f;
static constexpr float EPSF  = 2.2204460492503131e-16f;

typedef __bf16 bf16x8 __attribute__((ext_vector_type(8)));
typedef float floatx4 __attribute__((ext_vector_type(4)));
typedef unsigned long long u64;

// ordered-float encoding: monotone map float -> u32 (smaller float => smaller u32)
__device__ __forceinline__ unsigned int f2o(float f) {
  unsigned int u = __float_as_uint(f);
  return (u & 0x80000000u) ? ~u : (u | 0x80000000u);
}

__device__ __forceinline__ u64 umin64(u64 a, u64 b) { return a < b ? a : b; }

__device__ __forceinline__ bf16x8 cvt8(const float4 f0, const float4 f1) {
  bf16x8 h;
  h[0] = (__bf16)f0.x; h[1] = (__bf16)f0.y; h[2] = (__bf16)f0.z; h[3] = (__bf16)f0.w;
  h[4] = (__bf16)f1.x; h[5] = (__bf16)f1.y; h[6] = (__bf16)f1.z; h[7] = (__bf16)f1.w;
  return h;
}

// ====== K1: gram tiles + sim1 blocks in ONE kernel (independent work, overlapped)
// gram tiles convert fp32->bf16 during LDS staging (bitwise same cast as before);
// the 4 diagonal tiles persist their bf16 strip to Fbf for final_kernel.
// sim1 blocks do sim = F.q + per-strip partial argmin -> p0 (no Fbf write anymore).
// grid 18*B; decode keeps all 18 blocks of one b on one XCD (b's F = 512KB -> L2).
__global__ __launch_bounds__(256) void k1_kernel(
    const float* __restrict__ F, const float* __restrict__ Q,
    __bf16* __restrict__ Fbf, float* __restrict__ simbuf,
    u64* __restrict__ p0, float* __restrict__ Dgp)
{
  __shared__ __align__(16) unsigned char smem[36864];
  const int g = blockIdx.x;
  const int xcd = g & 7, idx = g >> 3;
  const int bb = idx / 18, jj = idx - bb * 18;
  const int b = bb * 8 + xcd;               // blockIdx%8 ~ XCD: all of b's blocks co-locate
  const int t = threadIdx.x;
  const int wave = t >> 6, lane = t & 63;
  const int quad = lane >> 4, l15 = lane & 15;
  const float* Fb = F + (size_t)b * (K * D);

  if (jj < 10) {
    // ---------------- gram tile: 128 x 128 (lower triangle of 4x4 strips) ----------------
    static constexpr int TI[10] = {0,1,1,2,2,2,3,3,3,3};
    static constexpr int TJ[10] = {0,0,1,0,1,2,0,1,2,3};
    const int ti = TI[jj], tj = TJ[jj];
    const int r0 = ti * 128, c0 = tj * 128;
    const bool diag = (ti == tj);
    __bf16* Fbb = Fbf + (size_t)b * (K * D);
    __bf16 (*Asb)[72] = (__bf16(*)[72])smem;            // 128 x 72 bf16
    __bf16 (*Bsb)[72] = diag ? Asb : (__bf16(*)[72])(smem + 18432);
    const int srow = t >> 1, skh = (t & 1) * 32;

    floatx4 acc[2][8];
    #pragma unroll
    for (int i = 0; i < 2; ++i)
      #pragma unroll
      for (int n = 0; n < 8; ++n) acc[i][n] = (floatx4){0.f, 0.f, 0.f, 0.f};

    for (int kk = 0; kk < D; kk += 64) {
      __syncthreads();
      {
        const float* sa = Fb + (size_t)(r0 + srow) * D + kk + skh;
        #pragma unroll
        for (int i = 0; i < 4; ++i) {
          const float4 f0 = *(const float4*)(sa + i * 8);
          const float4 f1 = *(const float4*)(sa + i * 8 + 4);
          const bf16x8 h = cvt8(f0, f1);
          *(bf16x8*)&Asb[srow][skh + i * 8] = h;
          if (diag)   // persist bf16 F for final_kernel (disjoint strips across 4 diag tiles)
            *(bf16x8*)(Fbb + (size_t)(r0 + srow) * D + kk + skh + i * 8) = h;
        }
        if (!diag) {
          const float* sb = Fb + (size_t)(c0 + srow) * D + kk + skh;
          #pragma unroll
          for (int i = 0; i < 4; ++i) {
            const float4 f0 = *(const float4*)(sb + i * 8);
            const float4 f1 = *(const float4*)(sb + i * 8 + 4);
            *(bf16x8*)&Bsb[srow][skh + i * 8] = cvt8(f0, f1);
          }
        }
      }
      __syncthreads();
      #pragma unroll
      for (int k2 = 0; k2 < 64; k2 += 32) {
        bf16x8 af[2], bfr[8];
        #pragma unroll
        for (int tm = 0; tm < 2; ++tm)
          af[tm] = *(bf16x8*)&Asb[wave * 32 + tm * 16 + l15][k2 + quad * 8];
        #pragma unroll
        for (int tn = 0; tn < 8; ++tn)
          bfr[tn] = *(bf16x8*)&Bsb[tn * 16 + l15][k2 + quad * 8];
        #pragma unroll
        for (int tm = 0; tm < 2; ++tm)
          #pragma unroll
          for (int tn = 0; tn < 8; ++tn)
            acc[tm][tn] = __builtin_amdgcn_mfma_f32_16x16x32_bf16(af[tm], bfr[tn], acc[tm][tn], 0, 0, 0);
      }
    }

    // epilogue: exp (+zero diag on diag tiles), row sums + col sums
    float rs[8] = {0.f};
    float cs[8] = {0.f};
    #pragma unroll
    for (int tm = 0; tm < 2; ++tm) {
      const int lrb = wave * 32 + tm * 16 + quad * 4;
      #pragma unroll
      for (int tn = 0; tn < 8; ++tn) {
        const int lc = tn * 16 + l15;
        #pragma unroll
        for (int r = 0; r < 4; ++r) {
          float wv = __expf(acc[tm][tn][r]);
          if (diag && (lrb + r) == lc) wv = 0.f;
          rs[tm * 4 + r] += wv;
          cs[tn] += wv;
        }
      }
    }
    // row sums -> slot tj
    #pragma unroll
    for (int s = 0; s < 8; ++s) {
      float v = rs[s];
      v += __shfl_xor(v, 1, 64); v += __shfl_xor(v, 2, 64);
      v += __shfl_xor(v, 4, 64); v += __shfl_xor(v, 8, 64);
      if (l15 == 0) {
        const int r = r0 + wave * 32 + (s >> 2) * 16 + quad * 4 + (s & 3);
        Dgp[(size_t)tj * (128 * K) + (size_t)b * K + r] = v;
      }
    }
    // col sums -> slot ti (off-diag tiles only)
    if (!diag) {
      #pragma unroll
      for (int tn = 0; tn < 8; ++tn) {
        cs[tn] += __shfl_xor(cs[tn], 16, 64);
        cs[tn] += __shfl_xor(cs[tn], 32, 64);
      }
      __syncthreads();                       // done with Asb/Bsb
      float* csum = (float*)smem;            // 4 x 128 floats
      if (lane < 16) {
        #pragma unroll
        for (int tn = 0; tn < 8; ++tn)
          csum[wave * 128 + tn * 16 + l15] = cs[tn];
      }
      __syncthreads();
      if (t < 128) {
        const float s = csum[t] + csum[128 + t] + csum[256 + t] + csum[384 + t];
        Dgp[(size_t)ti * (128 * K) + (size_t)b * K + c0 + t] = s;
      }
    }
  } else {
    // ---------------- sim1 strip: 64 rows, dot with q + partial argmin ----------------
    const int r0v = (jj - 10) * 64;
    float* qs = (float*)smem;
    u64* wred = (u64*)(smem + 1024);
    const int sub = lane >> 4, cg = lane & 15;
    qs[t] = Q[(size_t)b * D + t];
    __syncthreads();

    u64 best = ~0ULL;
    #pragma unroll
    for (int pass = 0; pass < 4; ++pass) {
      const int r = r0v + pass * 16 + wave * 4 + sub;
      const float* fr = Fb + (size_t)r * D;
      float p = 0.f;
      #pragma unroll
      for (int q = 0; q < 2; ++q) {
        const int c = q * 128 + cg * 8;
        const float4 f0 = *(const float4*)(fr + c);
        const float4 f1 = *(const float4*)(fr + c + 4);
        const float4 q0 = *(const float4*)(qs + c);
        const float4 q1 = *(const float4*)(qs + c + 4);
        p += f0.x*q0.x + f0.y*q0.y + f0.z*q0.z + f0.w*q0.w
           + f1.x*q1.x + f1.y*q1.y + f1.z*q1.z + f1.w*q1.w;
      }
      p += __shfl_xor(p, 1, 64); p += __shfl_xor(p, 2, 64);
      p += __shfl_xor(p, 4, 64); p += __shfl_xor(p, 8, 64);
      if (cg == 0) {
        simbuf[(size_t)b * K + r] = p;
        best = umin64(best, ((u64)f2o(p) << 32) | (unsigned int)r);
      }
    }
    best = umin64(best, __shfl_xor(best, 16, 64));
    best = umin64(best, __shfl_xor(best, 32, 64));
    if (lane == 0) wred[wave] = best;
    __syncthreads();
    if (t == 0)
      p0[b * 8 + (jj - 10)] =
          umin64(umin64(wred[0], wred[1]), umin64(wred[2], wred[3]));
  }
}

// ====== K2: sim2 quarter (fp32-exact), needs complete p0 ======
__global__ __launch_bounds__(256) void sim2_kernel(
    const float* __restrict__ F, const float* __restrict__ simbuf,
    const u64* __restrict__ p0, u64* __restrict__ p1)
{
  __shared__ __align__(16) float qs[D];
  __shared__ u64 wred[4];
  const int id2 = blockIdx.x;
  const int b = id2 & 127, s = id2 >> 7;
  const int r0 = s * 128;
  const float* Fb = F + (size_t)b * (K * D);
  const int t = threadIdx.x;
  const int wave = t >> 6, lane = t & 63;
  const int sub = lane >> 4, cg = lane & 15;

  u64 e0 = p0[b * 8];
  #pragma unroll
  for (int i = 1; i < 8; ++i) e0 = umin64(e0, p0[b * 8 + i]);
  const int a0 = (int)(e0 & 0xffffffffu);

  qs[t] = Fb[(size_t)a0 * D + t];
  __syncthreads();

  u64 best = ~0ULL;
  #pragma unroll
  for (int pass = 0; pass < 8; ++pass) {
    const int r = r0 + pass * 16 + wave * 4 + sub;
    const float* fr = Fb + (size_t)r * D;
    float p = 0.f;
    #pragma unroll
    for (int q = 0; q < 2; ++q) {
      const int c = q * 128 + cg * 8;
      const float4 f0 = *(const float4*)(fr + c);
      const float4 f1 = *(const float4*)(fr + c + 4);
      const float4 q0 = *(const float4*)(qs + c);
      const float4 q1 = *(const float4*)(qs + c + 4);
      p += f0.x*q0.x + f0.y*q0.y + f0.z*q0.z + f0.w*q0.w
         + f1.x*q1.x + f1.y*q1.y + f1.z*q1.z + f1.w*q1.w;
    }
    p += __shfl_xor(p, 1, 64); p += __shfl_xor(p, 2, 64);
    p += __shfl_xor(p, 4, 64); p += __shfl_xor(p, 8, 64);
    if (cg == 0) {
      const float m = fmaxf(simbuf[(size_t)b * K + r], p);
      best = umin64(best, ((u64)f2o(m) << 32) | (unsigned int)r);
    }
  }
  best = umin64(best, __shfl_xor(best, 16, 64));
  best = umin64(best, __shfl_xor(best, 32, 64));
  if (lane == 0) wred[wave] = best;
  __syncthreads();
  if (t == 0)
    p1[b * 4 + s] =
        umin64(umin64(wred[0], wred[1]), umin64(wred[2], wred[3]));
}

// ===== final: out = y + alpha*R*y + alpha/(1-alpha) * v * (v.y)  (NIT=1) =====
__global__ __launch_bounds__(256) void final_kernel(
    const float* __restrict__ F, const __bf16* __restrict__ Fbf,
    const float* __restrict__ Dgp, const u64* __restrict__ p0,
    const u64* __restrict__ p1, float* __restrict__ out)
{
  const int b = blockIdx.y;
  const int r0 = blockIdx.x * 128;
  const float* Fb = F + (size_t)b * (K * D);
  const __bf16* Fbb = Fbf + (size_t)b * (K * D);
  __shared__ __align__(16) float qa[D], qb[D];
  __shared__ float dinv_s[K], sqd_s[K];
  __shared__ float red[4];
  const int t = threadIdx.x;
  const int wave = t >> 6, lane = t & 63;
  const int sub = lane >> 4, cg = lane & 15;

  u64 e0 = p0[b * 8];
  #pragma unroll
  for (int i = 1; i < 8; ++i) e0 = umin64(e0, p0[b * 8 + i]);
  u64 e1 = p1[b * 4];
  #pragma unroll
  for (int i = 1; i < 4; ++i) e1 = umin64(e1, p1[b * 4 + i]);
  const int a0 = (int)(e0 & 0xffffffffu);
  const int a1 = (int)(e1 & 0xffffffffu);

  qa[t] = Fb[(size_t)a0 * D + t];
  qb[t] = Fb[(size_t)a1 * D + t];
  float dsum = 0.f;
  for (int k = t; k < K; k += 256) {
    const size_t o = (size_t)b * K + k;
    const float d = Dgp[o] + Dgp[(size_t)128 * K + o]
                  + Dgp[(size_t)2 * 128 * K + o] + Dgp[(size_t)3 * 128 * K + o];
    dinv_s[k] = 1.0f / sqrtf(d + EPSF);
    sqd_s[k] = sqrtf(d);
    dsum += d;
  }
  #pragma unroll
  for (int off = 32; off >= 1; off >>= 1) dsum += __shfl_down(dsum, off, 64);
  if (lane == 0) red[wave] = dsum;
  __syncthreads();
  const float vn = 1.0f / sqrtf(red[0] + red[1] + red[2] + red[3]);
  const float s0 = vn * sqd_s[a0], s1 = vn * sqd_s[a1];   // v[a0], v[a1]
  const float dia0 = dinv_s[a0], dia1 = dinv_s[a1];
  const float c99 = ALPHA / (1.0f - ALPHA);

  float2* ob = (float2*)(out + (size_t)b * K * 2);

  #pragma unroll
  for (int pass = 0; pass < 8; ++pass) {
    const int r = r0 + pass * 16 + wave * 4 + sub;
    const __bf16* fr = Fbb + (size_t)r * D;
    float pa = 0.f, pb = 0.f;
    #pragma unroll
    for (int q = 0; q < 2; ++q) {
      const int c = q * 128 + cg * 8;
      const uint4 wv = *(const uint4*)(fr + c);
      const float4 a0v = *(const float4*)(qa + c);
      const float4 a1v = *(const float4*)(qa + c + 4);
      const float4 b0v = *(const float4*)(qb + c);
      const float4 b1v = *(const float4*)(qb + c + 4);
      const float w0 = __uint_as_float(wv.x << 16);
      const float w1 = __uint_as_float(wv.x & 0xffff0000u);
      const float w2 = __uint_as_float(wv.y << 16);
      const float w3 = __uint_as_float(wv.y & 0xffff0000u);
      const float w4 = __uint_as_float(wv.z << 16);
      const float w5 = __uint_as_float(wv.z & 0xffff0000u);
      const float w6 = __uint_as_float(wv.w << 16);
      const float w7 = __uint_as_float(wv.w & 0xffff0000u);
      pa += w0*a0v.x + w1*a0v.y + w2*a0v.z + w3*a0v.w
          + w4*a1v.x + w5*a1v.y + w6*a1v.z + w7*a1v.w;
      pb += w0*b0v.x + w1*b0v.y + w2*b0v.z + w3*b0v.w
          + w4*b1v.x + w5*b1v.y + w6*b1v.z + w7*b1v.w;
    }
    pa += __shfl_xor(pa, 1, 64); pa += __shfl_xor(pa, 2, 64);
    pa += __shfl_xor(pa, 4, 64); pa += __shfl_xor(pa, 8, 64);
    pb += __shfl_xor(pb, 1, 64); pb += __shfl_xor(pb, 2, 64);
    pb += __shfl_xor(pb, 4, 64); pb += __shfl_xor(pb, 8, 64);
    if (cg == 0) {
      const float q0 = ((r == a0) ? 0.f : __expf(pa)) * dia0;
      const float q1 = ((r == a1) ? 0.f : __expf(pb)) * dia1;
      const float di = dinv_s[r];
      const float vr = vn * sqd_s[r];                      // v[r]
      const float w0n = ALPHA * (di * q0 - vr * s0);
      const float w1n = ALPHA * (di * q1 - vr * s1);
      float2 o;
      o.x = ((r == a0) ? 1.f : 0.f) + w0n + c99 * s0 * vr;
      o.y = ((r == a1) ? 1.f : 0.f) + w1n + c99 * s1 * vr;
      ob[r] = o;
    }
  }
}

// ==========================================================================
extern "C" void kernel_launch(void* const* d_in, const int* in_sizes, int n_in,
                              void* d_out, int out_size, void* d_ws, size_t ws_size,
                              hipStream_t stream) {
  const float* F = (const float*)d_in[0];   // [B,K,D]
  const float* Q = (const float*)d_in[1];   // [B,D]
  float* out = (float*)d_out;               // [B,K,2]
  const int B = in_sizes[1] / D;            // 128

  __bf16* Fbf = (__bf16*)d_ws;                           // B*K*D bf16 (33.5 MB)
  float* Dgp  = (float*)(Fbf + (size_t)B * K * D);       // 4*B*K (partial degrees)
  float* simb = Dgp + (size_t)4 * B * K;                 // B*K
  u64*   p0   = (u64*)(simb + (size_t)B * K);            // B*8
  u64*   p1   = p0 + (size_t)B * 8;                      // B*4

  k1_kernel<<<18 * B, 256, 0, stream>>>(F, Q, Fbf, simb, p0, Dgp);
  sim2_kernel<<<4 * B, 256, 0, stream>>>(F, simb, p0, p1);
  final_kernel<<<dim3(4, B), 256, 0, stream>>>(F, Fbf, Dgp, p0, p1, out);
}

// Round 3
// 137.766 us; speedup vs baseline: 1.1820x; 1.1820x over previous
//
#include <hip/hip_runtime.h>
#include <math.h>

static constexpr int K = 512;
static constexpr int D = 256;
static constexpr float ALPHA = 0.99f;
static constexpr float EPSF  = 2.2204460492503131e-16f;

typedef __bf16 bf16x8 __attribute__((ext_vector_type(8)));
typedef float floatx4 __attribute__((ext_vector_type(4)));
typedef unsigned long long u64;

// ordered-float encoding: monotone map float -> u32 (smaller float => smaller u32)
__device__ __forceinline__ unsigned int f2o(float f) {
  unsigned int u = __float_as_uint(f);
  return (u & 0x80000000u) ? ~u : (u | 0x80000000u);
}

__device__ __forceinline__ u64 umin64(u64 a, u64 b) { return a < b ? a : b; }

// ====== sim1: sim = F.q, per-block partial argmin; ALSO emits bf16 F ======
// grid (16, B): block covers 32 rows; partial best -> p0[b*16 + bx]
__global__ __launch_bounds__(256) void sim1_kernel(
    const float* __restrict__ F, const float* __restrict__ Q,
    __bf16* __restrict__ Fbf, float* __restrict__ simbuf, u64* __restrict__ p0)
{
  const int b = blockIdx.y;
  const int r0 = blockIdx.x * 32;
  const float* Fb = F + (size_t)b * (K * D);
  __bf16* Fbb = Fbf + (size_t)b * (K * D);
  __shared__ __align__(16) float qs[D];
  __shared__ u64 wred[4];
  const int t = threadIdx.x;
  const int wave = t >> 6, lane = t & 63;
  const int sub = lane >> 4, cg = lane & 15;
  qs[t] = Q[(size_t)b * D + t];
  __syncthreads();

  u64 best = ~0ULL;
  #pragma unroll
  for (int pass = 0; pass < 2; ++pass) {
    const int r = r0 + pass * 16 + wave * 4 + sub;
    const float* fr = Fb + (size_t)r * D;
    float p = 0.f;
    #pragma unroll
    for (int q = 0; q < 2; ++q) {
      const int c = q * 128 + cg * 8;
      const float4 f0 = *(const float4*)(fr + c);
      const float4 f1 = *(const float4*)(fr + c + 4);
      const float4 q0 = *(const float4*)(qs + c);
      const float4 q1 = *(const float4*)(qs + c + 4);
      p += f0.x*q0.x + f0.y*q0.y + f0.z*q0.z + f0.w*q0.w
         + f1.x*q1.x + f1.y*q1.y + f1.z*q1.z + f1.w*q1.w;
      bf16x8 h;
      h[0] = (__bf16)f0.x; h[1] = (__bf16)f0.y; h[2] = (__bf16)f0.z; h[3] = (__bf16)f0.w;
      h[4] = (__bf16)f1.x; h[5] = (__bf16)f1.y; h[6] = (__bf16)f1.z; h[7] = (__bf16)f1.w;
      *(bf16x8*)(Fbb + (size_t)r * D + c) = h;
    }
    p += __shfl_xor(p, 1, 64); p += __shfl_xor(p, 2, 64);
    p += __shfl_xor(p, 4, 64); p += __shfl_xor(p, 8, 64);
    if (cg == 0) {
      simbuf[(size_t)b * K + r] = p;
      best = umin64(best, ((u64)f2o(p) << 32) | (unsigned int)r);
    }
  }
  best = umin64(best, __shfl_xor(best, 16, 64));
  best = umin64(best, __shfl_xor(best, 32, 64));
  if (lane == 0) wred[wave] = best;
  __syncthreads();
  if (t == 0)
    p0[b * 16 + blockIdx.x] =
        umin64(umin64(wred[0], wred[1]), umin64(wred[2], wred[3]));
}

// ====== fused: blocks <512 = sim2 quarters (fp32-exact); 512..1791 = gram tiles ======
__global__ __launch_bounds__(256) void fused_kernel(
    const float* __restrict__ F, const __bf16* __restrict__ Fbf,
    const float* __restrict__ simbuf, const u64* __restrict__ p0,
    u64* __restrict__ p1, float* __restrict__ Dgp)
{
  __shared__ __align__(16) unsigned char smem[36864];
  const int id = blockIdx.x;
  const int t = threadIdx.x;
  const int wave = t >> 6, lane = t & 63;
  const int quad = lane >> 4, l15 = lane & 15;

  if (id >= 512) {
    // ---------------- gram tile: 128 x 128 ----------------
    const int T = id - 512;
    const int b = T & 127;
    const int tid = T >> 7;                 // 0..9
    static constexpr int TI[10] = {0,1,1,2,2,2,3,3,3,3};
    static constexpr int TJ[10] = {0,0,1,0,1,2,0,1,2,3};
    const int ti = TI[tid], tj = TJ[tid];
    const int r0 = ti * 128, c0 = tj * 128;
    const bool diag = (ti == tj);
    const __bf16* Fb = Fbf + (size_t)b * (K * D);
    __bf16 (*Asb)[72] = (__bf16(*)[72])smem;            // 128 x 72 bf16
    __bf16 (*Bsb)[72] = diag ? Asb : (__bf16(*)[72])(smem + 18432);
    const int srow = t >> 1, skh = (t & 1) * 32;

    floatx4 acc[2][8];
    #pragma unroll
    for (int i = 0; i < 2; ++i)
      #pragma unroll
      for (int j = 0; j < 8; ++j) acc[i][j] = (floatx4){0.f, 0.f, 0.f, 0.f};

    for (int kk = 0; kk < D; kk += 64) {
      __syncthreads();
      {
        const __bf16* sa = Fb + (size_t)(r0 + srow) * D + kk + skh;
        *(uint4*)&Asb[srow][skh +  0] = *(const uint4*)(sa +  0);
        *(uint4*)&Asb[srow][skh +  8] = *(const uint4*)(sa +  8);
        *(uint4*)&Asb[srow][skh + 16] = *(const uint4*)(sa + 16);
        *(uint4*)&Asb[srow][skh + 24] = *(const uint4*)(sa + 24);
        if (!diag) {
          const __bf16* sb = Fb + (size_t)(c0 + srow) * D + kk + skh;
          *(uint4*)&Bsb[srow][skh +  0] = *(const uint4*)(sb +  0);
          *(uint4*)&Bsb[srow][skh +  8] = *(const uint4*)(sb +  8);
          *(uint4*)&Bsb[srow][skh + 16] = *(const uint4*)(sb + 16);
          *(uint4*)&Bsb[srow][skh + 24] = *(const uint4*)(sb + 24);
        }
      }
      __syncthreads();
      #pragma unroll
      for (int k2 = 0; k2 < 64; k2 += 32) {
        bf16x8 af[2], bf[8];
        #pragma unroll
        for (int tm = 0; tm < 2; ++tm)
          af[tm] = *(bf16x8*)&Asb[wave * 32 + tm * 16 + l15][k2 + quad * 8];
        #pragma unroll
        for (int tn = 0; tn < 8; ++tn)
          bf[tn] = *(bf16x8*)&Bsb[tn * 16 + l15][k2 + quad * 8];
        #pragma unroll
        for (int tm = 0; tm < 2; ++tm)
          #pragma unroll
          for (int tn = 0; tn < 8; ++tn)
            acc[tm][tn] = __builtin_amdgcn_mfma_f32_16x16x32_bf16(af[tm], bf[tn], acc[tm][tn], 0, 0, 0);
      }
    }

    // epilogue: exp (+zero diag on diag tiles), row sums + col sums
    float rs[8] = {0.f};
    float cs[8] = {0.f};
    #pragma unroll
    for (int tm = 0; tm < 2; ++tm) {
      const int lrb = wave * 32 + tm * 16 + quad * 4;
      #pragma unroll
      for (int tn = 0; tn < 8; ++tn) {
        const int lc = tn * 16 + l15;
        #pragma unroll
        for (int r = 0; r < 4; ++r) {
          float wv = __expf(acc[tm][tn][r]);
          if (diag && (lrb + r) == lc) wv = 0.f;
          rs[tm * 4 + r] += wv;
          cs[tn] += wv;
        }
      }
    }
    // row sums -> slot tj
    #pragma unroll
    for (int s = 0; s < 8; ++s) {
      float v = rs[s];
      v += __shfl_xor(v, 1, 64); v += __shfl_xor(v, 2, 64);
      v += __shfl_xor(v, 4, 64); v += __shfl_xor(v, 8, 64);
      if (l15 == 0) {
        const int r = r0 + wave * 32 + (s >> 2) * 16 + quad * 4 + (s & 3);
        Dgp[(size_t)tj * (128 * K) + (size_t)b * K + r] = v;
      }
    }
    // col sums -> slot ti (off-diag tiles only)
    if (!diag) {
      #pragma unroll
      for (int tn = 0; tn < 8; ++tn) {
        cs[tn] += __shfl_xor(cs[tn], 16, 64);
        cs[tn] += __shfl_xor(cs[tn], 32, 64);
      }
      __syncthreads();                       // done with Asb/Bsb
      float* csum = (float*)smem;            // 4 x 128 floats
      if (lane < 16) {
        #pragma unroll
        for (int tn = 0; tn < 8; ++tn)
          csum[wave * 128 + tn * 16 + l15] = cs[tn];
      }
      __syncthreads();
      if (t < 128) {
        const float s = csum[t] + csum[128 + t] + csum[256 + t] + csum[384 + t];
        Dgp[(size_t)ti * (128 * K) + (size_t)b * K + c0 + t] = s;
      }
    }
  } else {
    // ---------------- sim2 quarter (fp32-exact), ids 0..511 ----------------
    const int b = id & 127, s = id >> 7;
    const int r0 = s * 128;
    const float* Fb = F + (size_t)b * (K * D);
    float* qs = (float*)smem;
    u64* wred = (u64*)(smem + 1024);
    const int sub = lane >> 4, cg = lane & 15;

    u64 e0 = p0[b * 16];
    #pragma unroll
    for (int i = 1; i < 16; ++i) e0 = umin64(e0, p0[b * 16 + i]);
    const int a0 = (int)(e0 & 0xffffffffu);

    qs[t] = Fb[(size_t)a0 * D + t];
    __syncthreads();

    u64 best = ~0ULL;
    #pragma unroll
    for (int pass = 0; pass < 8; ++pass) {
      const int r = r0 + pass * 16 + wave * 4 + sub;
      const float* fr = Fb + (size_t)r * D;
      float p = 0.f;
      #pragma unroll
      for (int q = 0; q < 2; ++q) {
        const int c = q * 128 + cg * 8;
        const float4 f0 = *(const float4*)(fr + c);
        const float4 f1 = *(const float4*)(fr + c + 4);
        const float4 q0 = *(const float4*)(qs + c);
        const float4 q1 = *(const float4*)(qs + c + 4);
        p += f0.x*q0.x + f0.y*q0.y + f0.z*q0.z + f0.w*q0.w
           + f1.x*q1.x + f1.y*q1.y + f1.z*q1.z + f1.w*q1.w;
      }
      p += __shfl_xor(p, 1, 64); p += __shfl_xor(p, 2, 64);
      p += __shfl_xor(p, 4, 64); p += __shfl_xor(p, 8, 64);
      if (cg == 0) {
        const float m = fmaxf(simbuf[(size_t)b * K + r], p);
        best = umin64(best, ((u64)f2o(m) << 32) | (unsigned int)r);
      }
    }
    best = umin64(best, __shfl_xor(best, 16, 64));
    best = umin64(best, __shfl_xor(best, 32, 64));
    if (lane == 0) wred[wave] = best;
    __syncthreads();
    if (t == 0)
      p1[b * 4 + s] =
          umin64(umin64(wred[0], wred[1]), umin64(wred[2], wred[3]));
  }
}

// ===== final: out = y + alpha*R*y + alpha/(1-alpha) * v * (v.y)  (NIT=1) =====
// grid (8, B): 64 rows per block. degrees = sum of 4 partial slots;
// anchor-column GEMVs read bf16 F.
__global__ __launch_bounds__(256) void final_kernel(
    const float* __restrict__ F, const __bf16* __restrict__ Fbf,
    const float* __restrict__ Dgp, const u64* __restrict__ p0,
    const u64* __restrict__ p1, float* __restrict__ out)
{
  const int b = blockIdx.y;
  const int r0 = blockIdx.x * 64;
  const float* Fb = F + (size_t)b * (K * D);
  const __bf16* Fbb = Fbf + (size_t)b * (K * D);
  __shared__ __align__(16) float qa[D], qb[D];
  __shared__ float dinv_s[K], sqd_s[K];
  __shared__ float red[4];
  const int t = threadIdx.x;
  const int wave = t >> 6, lane = t & 63;
  const int sub = lane >> 4, cg = lane & 15;

  u64 e0 = p0[b * 16];
  #pragma unroll
  for (int i = 1; i < 16; ++i) e0 = umin64(e0, p0[b * 16 + i]);
  u64 e1 = p1[b * 4];
  #pragma unroll
  for (int i = 1; i < 4; ++i) e1 = umin64(e1, p1[b * 4 + i]);
  const int a0 = (int)(e0 & 0xffffffffu);
  const int a1 = (int)(e1 & 0xffffffffu);

  qa[t] = Fb[(size_t)a0 * D + t];
  qb[t] = Fb[(size_t)a1 * D + t];
  float dsum = 0.f;
  for (int k = t; k < K; k += 256) {
    const size_t o = (size_t)b * K + k;
    const float d = Dgp[o] + Dgp[(size_t)128 * K + o]
                  + Dgp[(size_t)2 * 128 * K + o] + Dgp[(size_t)3 * 128 * K + o];
    dinv_s[k] = 1.0f / sqrtf(d + EPSF);
    sqd_s[k] = sqrtf(d);
    dsum += d;
  }
  #pragma unroll
  for (int off = 32; off >= 1; off >>= 1) dsum += __shfl_down(dsum, off, 64);
  if (lane == 0) red[wave] = dsum;
  __syncthreads();
  const float vn = 1.0f / sqrtf(red[0] + red[1] + red[2] + red[3]);
  const float s0 = vn * sqd_s[a0], s1 = vn * sqd_s[a1];   // v[a0], v[a1]
  const float dia0 = dinv_s[a0], dia1 = dinv_s[a1];
  const float c99 = ALPHA / (1.0f - ALPHA);

  float2* ob = (float2*)(out + (size_t)b * K * 2);

  #pragma unroll
  for (int pass = 0; pass < 4; ++pass) {
    const int r = r0 + pass * 16 + wave * 4 + sub;
    const __bf16* fr = Fbb + (size_t)r * D;
    float pa = 0.f, pb = 0.f;
    #pragma unroll
    for (int q = 0; q < 2; ++q) {
      const int c = q * 128 + cg * 8;
      const uint4 wv = *(const uint4*)(fr + c);
      const float4 a0v = *(const float4*)(qa + c);
      const float4 a1v = *(const float4*)(qa + c + 4);
      const float4 b0v = *(const float4*)(qb + c);
      const float4 b1v = *(const float4*)(qb + c + 4);
      const float w0 = __uint_as_float(wv.x << 16);
      const float w1 = __uint_as_float(wv.x & 0xffff0000u);
      const float w2 = __uint_as_float(wv.y << 16);
      const float w3 = __uint_as_float(wv.y & 0xffff0000u);
      const float w4 = __uint_as_float(wv.z << 16);
      const float w5 = __uint_as_float(wv.z & 0xffff0000u);
      const float w6 = __uint_as_float(wv.w << 16);
      const float w7 = __uint_as_float(wv.w & 0xffff0000u);
      pa += w0*a0v.x + w1*a0v.y + w2*a0v.z + w3*a0v.w
          + w4*a1v.x + w5*a1v.y + w6*a1v.z + w7*a1v.w;
      pb += w0*b0v.x + w1*b0v.y + w2*b0v.z + w3*b0v.w
          + w4*b1v.x + w5*b1v.y + w6*b1v.z + w7*b1v.w;
    }
    pa += __shfl_xor(pa, 1, 64); pa += __shfl_xor(pa, 2, 64);
    pa += __shfl_xor(pa, 4, 64); pa += __shfl_xor(pa, 8, 64);
    pb += __shfl_xor(pb, 1, 64); pb += __shfl_xor(pb, 2, 64);
    pb += __shfl_xor(pb, 4, 64); pb += __shfl_xor(pb, 8, 64);
    if (cg == 0) {
      const float q0 = ((r == a0) ? 0.f : __expf(pa)) * dia0;
      const float q1 = ((r == a1) ? 0.f : __expf(pb)) * dia1;
      const float di = dinv_s[r];
      const float vr = vn * sqd_s[r];                      // v[r]
      const float w0n = ALPHA * (di * q0 - vr * s0);
      const float w1n = ALPHA * (di * q1 - vr * s1);
      float2 o;
      o.x = ((r == a0) ? 1.f : 0.f) + w0n + c99 * s0 * vr;
      o.y = ((r == a1) ? 1.f : 0.f) + w1n + c99 * s1 * vr;
      ob[r] = o;
    }
  }
}

// ==========================================================================
extern "C" void kernel_launch(void* const* d_in, const int* in_sizes, int n_in,
                              void* d_out, int out_size, void* d_ws, size_t ws_size,
                              hipStream_t stream) {
  const float* F = (const float*)d_in[0];   // [B,K,D]
  const float* Q = (const float*)d_in[1];   // [B,D]
  float* out = (float*)d_out;               // [B,K,2]
  const int B = in_sizes[1] / D;            // 128

  __bf16* Fbf = (__bf16*)d_ws;                           // B*K*D bf16 (33.5 MB)
  float* Dgp  = (float*)(Fbf + (size_t)B * K * D);       // 4*B*K (partial degrees)
  float* simb = Dgp + (size_t)4 * B * K;                 // B*K
  u64*   p0   = (u64*)(simb + (size_t)B * K);            // B*16
  u64*   p1   = p0 + (size_t)B * 16;                     // B*4

  sim1_kernel<<<dim3(16, B), 256, 0, stream>>>(F, Q, Fbf, simb, p0);
  fused_kernel<<<1792, 256, 0, stream>>>(F, Fbf, simb, p0, p1, Dgp);
  final_kernel<<<dim3(8, B), 256, 0, stream>>>(F, Fbf, Dgp, p0, p1, out);
}

// Round 4
// 137.029 us; speedup vs baseline: 1.1883x; 1.0054x over previous
//
#include <hip/hip_runtime.h>
#include <math.h>

static constexpr int K = 512;
static constexpr int D = 256;
static constexpr float ALPHA = 0.99f;
static constexpr float EPSF  = 2.2204460492503131e-16f;

typedef __bf16 bf16x8 __attribute__((ext_vector_type(8)));
typedef float floatx4 __attribute__((ext_vector_type(4)));
typedef unsigned long long u64;

// ordered-float encoding: monotone map float -> u32 (smaller float => smaller u32)
__device__ __forceinline__ unsigned int f2o(float f) {
  unsigned int u = __float_as_uint(f);
  return (u & 0x80000000u) ? ~u : (u | 0x80000000u);
}

__device__ __forceinline__ u64 umin64(u64 a, u64 b) { return a < b ? a : b; }

// ====== sim1: sim = F.q, per-block partial argmin; ALSO emits bf16 F ======
// grid (16, B): block covers 32 rows; partial best -> p0[b*16 + bx]
__global__ __launch_bounds__(256) void sim1_kernel(
    const float* __restrict__ F, const float* __restrict__ Q,
    __bf16* __restrict__ Fbf, float* __restrict__ simbuf, u64* __restrict__ p0)
{
  const int b = blockIdx.y;
  const int r0 = blockIdx.x * 32;
  const float* Fb = F + (size_t)b * (K * D);
  __bf16* Fbb = Fbf + (size_t)b * (K * D);
  __shared__ __align__(16) float qs[D];
  __shared__ u64 wred[4];
  const int t = threadIdx.x;
  const int wave = t >> 6, lane = t & 63;
  const int sub = lane >> 4, cg = lane & 15;
  qs[t] = Q[(size_t)b * D + t];
  __syncthreads();

  u64 best = ~0ULL;
  #pragma unroll
  for (int pass = 0; pass < 2; ++pass) {
    const int r = r0 + pass * 16 + wave * 4 + sub;
    const float* fr = Fb + (size_t)r * D;
    float p = 0.f;
    #pragma unroll
    for (int q = 0; q < 2; ++q) {
      const int c = q * 128 + cg * 8;
      const float4 f0 = *(const float4*)(fr + c);
      const float4 f1 = *(const float4*)(fr + c + 4);
      const float4 q0 = *(const float4*)(qs + c);
      const float4 q1 = *(const float4*)(qs + c + 4);
      p += f0.x*q0.x + f0.y*q0.y + f0.z*q0.z + f0.w*q0.w
         + f1.x*q1.x + f1.y*q1.y + f1.z*q1.z + f1.w*q1.w;
      bf16x8 h;
      h[0] = (__bf16)f0.x; h[1] = (__bf16)f0.y; h[2] = (__bf16)f0.z; h[3] = (__bf16)f0.w;
      h[4] = (__bf16)f1.x; h[5] = (__bf16)f1.y; h[6] = (__bf16)f1.z; h[7] = (__bf16)f1.w;
      *(bf16x8*)(Fbb + (size_t)r * D + c) = h;
    }
    p += __shfl_xor(p, 1, 64); p += __shfl_xor(p, 2, 64);
    p += __shfl_xor(p, 4, 64); p += __shfl_xor(p, 8, 64);
    if (cg == 0) {
      simbuf[(size_t)b * K + r] = p;
      best = umin64(best, ((u64)f2o(p) << 32) | (unsigned int)r);
    }
  }
  best = umin64(best, __shfl_xor(best, 16, 64));
  best = umin64(best, __shfl_xor(best, 32, 64));
  if (lane == 0) wred[wave] = best;
  __syncthreads();
  if (t == 0)
    p0[b * 16 + blockIdx.x] =
        umin64(umin64(wred[0], wred[1]), umin64(wred[2], wred[3]));
}

// ====== fused (512 threads): blocks <1280 = gram tiles (8 waves); rest = sim2 ======
__global__ __launch_bounds__(512) void fused_kernel(
    const float* __restrict__ F, const __bf16* __restrict__ Fbf,
    const float* __restrict__ simbuf, const u64* __restrict__ p0,
    u64* __restrict__ p1, float* __restrict__ Dgp)
{
  __shared__ __align__(16) unsigned char smem[36864];
  const int id = blockIdx.x;
  const int t = threadIdx.x;
  const int wave = t >> 6, lane = t & 63;
  const int quad = lane >> 4, l15 = lane & 15;

  if (id < 1280) {
    // ---------------- gram tile: 128 x 128, 8 waves (wave w -> rows w*16..w*16+15) ----
    const int b = id & 127;
    const int tid = id >> 7;                 // 0..9
    static constexpr int TI[10] = {0,1,1,2,2,2,3,3,3,3};
    static constexpr int TJ[10] = {0,0,1,0,1,2,0,1,2,3};
    const int ti = TI[tid], tj = TJ[tid];
    const int r0 = ti * 128, c0 = tj * 128;
    const bool diag = (ti == tj);
    const __bf16* Fb = Fbf + (size_t)b * (K * D);
    __bf16 (*Asb)[72] = (__bf16(*)[72])smem;            // 128 x 72 bf16
    __bf16 (*Bsb)[72] = diag ? Asb : (__bf16(*)[72])(smem + 18432);
    const int srow = t >> 2, skh = (t & 3) * 16;        // 512 thr: 4 thr/row, 16 cols each

    floatx4 acc[8];
    #pragma unroll
    for (int n = 0; n < 8; ++n) acc[n] = (floatx4){0.f, 0.f, 0.f, 0.f};

    for (int kk = 0; kk < D; kk += 64) {
      __syncthreads();
      {
        const __bf16* sa = Fb + (size_t)(r0 + srow) * D + kk + skh;
        *(uint4*)&Asb[srow][skh + 0] = *(const uint4*)(sa + 0);
        *(uint4*)&Asb[srow][skh + 8] = *(const uint4*)(sa + 8);
        if (!diag) {
          const __bf16* sb = Fb + (size_t)(c0 + srow) * D + kk + skh;
          *(uint4*)&Bsb[srow][skh + 0] = *(const uint4*)(sb + 0);
          *(uint4*)&Bsb[srow][skh + 8] = *(const uint4*)(sb + 8);
        }
      }
      __syncthreads();
      #pragma unroll
      for (int k2 = 0; k2 < 64; k2 += 32) {
        const bf16x8 af = *(bf16x8*)&Asb[wave * 16 + l15][k2 + quad * 8];
        #pragma unroll
        for (int tn = 0; tn < 8; ++tn) {
          const bf16x8 bfr = *(bf16x8*)&Bsb[tn * 16 + l15][k2 + quad * 8];
          acc[tn] = __builtin_amdgcn_mfma_f32_16x16x32_bf16(af, bfr, acc[tn], 0, 0, 0);
        }
      }
    }

    // epilogue: exp (+zero diag on diag tiles), row sums + col sums
    float rs[4] = {0.f, 0.f, 0.f, 0.f};
    float cs[8] = {0.f};
    const int lrb = wave * 16 + quad * 4;               // local row base of this thread
    #pragma unroll
    for (int tn = 0; tn < 8; ++tn) {
      const int lc = tn * 16 + l15;
      #pragma unroll
      for (int r = 0; r < 4; ++r) {
        float wv = __expf(acc[tn][r]);
        if (diag && (lrb + r) == lc) wv = 0.f;
        rs[r] += wv;
        cs[tn] += wv;
      }
    }
    // row sums -> slot tj
    #pragma unroll
    for (int s = 0; s < 4; ++s) {
      float v = rs[s];
      v += __shfl_xor(v, 1, 64); v += __shfl_xor(v, 2, 64);
      v += __shfl_xor(v, 4, 64); v += __shfl_xor(v, 8, 64);
      if (l15 == 0) {
        const int r = r0 + lrb + s;
        Dgp[(size_t)tj * (128 * K) + (size_t)b * K + r] = v;
      }
    }
    // col sums -> slot ti (off-diag tiles only)
    if (!diag) {
      #pragma unroll
      for (int tn = 0; tn < 8; ++tn) {
        cs[tn] += __shfl_xor(cs[tn], 16, 64);
        cs[tn] += __shfl_xor(cs[tn], 32, 64);
      }
      __syncthreads();                       // done with Asb/Bsb
      float* csum = (float*)smem;            // 8 x 128 floats
      if (lane < 16) {
        #pragma unroll
        for (int tn = 0; tn < 8; ++tn)
          csum[wave * 128 + tn * 16 + l15] = cs[tn];
      }
      __syncthreads();
      if (t < 128) {
        float s = 0.f;
        #pragma unroll
        for (int w = 0; w < 8; ++w) s += csum[w * 128 + t];
        Dgp[(size_t)ti * (128 * K) + (size_t)b * K + c0 + t] = s;
      }
    }
  } else {
    // ---------------- sim2 quarter (fp32-exact), ids 1280..1791, 512 thr ----------------
    const int id2 = id - 1280;
    const int b = id2 & 127, s = id2 >> 7;
    const int r0 = s * 128;
    const float* Fb = F + (size_t)b * (K * D);
    float* qs = (float*)smem;
    u64* wred = (u64*)(smem + 1024);

    u64 e0 = p0[b * 16];
    #pragma unroll
    for (int i = 1; i < 16; ++i) e0 = umin64(e0, p0[b * 16 + i]);
    const int a0 = (int)(e0 & 0xffffffffu);

    if (t < 256) qs[t] = Fb[(size_t)a0 * D + t];
    __syncthreads();

    u64 best = ~0ULL;
    #pragma unroll
    for (int pass = 0; pass < 4; ++pass) {
      const int r = r0 + pass * 32 + wave * 4 + quad;
      const float* fr = Fb + (size_t)r * D;
      float p = 0.f;
      #pragma unroll
      for (int q = 0; q < 2; ++q) {
        const int c = q * 128 + l15 * 8;
        const float4 f0 = *(const float4*)(fr + c);
        const float4 f1 = *(const float4*)(fr + c + 4);
        const float4 q0 = *(const float4*)(qs + c);
        const float4 q1 = *(const float4*)(qs + c + 4);
        p += f0.x*q0.x + f0.y*q0.y + f0.z*q0.z + f0.w*q0.w
           + f1.x*q1.x + f1.y*q1.y + f1.z*q1.z + f1.w*q1.w;
      }
      p += __shfl_xor(p, 1, 64); p += __shfl_xor(p, 2, 64);
      p += __shfl_xor(p, 4, 64); p += __shfl_xor(p, 8, 64);
      if (l15 == 0) {
        const float m = fmaxf(simbuf[(size_t)b * K + r], p);
        best = umin64(best, ((u64)f2o(m) << 32) | (unsigned int)r);
      }
    }
    best = umin64(best, __shfl_xor(best, 16, 64));
    best = umin64(best, __shfl_xor(best, 32, 64));
    if (lane == 0) wred[wave] = best;
    __syncthreads();
    if (t == 0) {
      u64 e = wred[0];
      #pragma unroll
      for (int w = 1; w < 8; ++w) e = umin64(e, wred[w]);
      p1[b * 4 + s] = e;
    }
  }
}

// ===== final: out = y + alpha*R*y + alpha/(1-alpha) * v * (v.y)  (NIT=1) =====
// grid (8, B): 64 rows per block. degrees = sum of 4 partial slots;
// anchor-column GEMVs read bf16 F.
__global__ __launch_bounds__(256) void final_kernel(
    const float* __restrict__ F, const __bf16* __restrict__ Fbf,
    const float* __restrict__ Dgp, const u64* __restrict__ p0,
    const u64* __restrict__ p1, float* __restrict__ out)
{
  const int b = blockIdx.y;
  const int r0 = blockIdx.x * 64;
  const float* Fb = F + (size_t)b * (K * D);
  const __bf16* Fbb = Fbf + (size_t)b * (K * D);
  __shared__ __align__(16) float qa[D], qb[D];
  __shared__ float dinv_s[K], sqd_s[K];
  __shared__ float red[4];
  const int t = threadIdx.x;
  const int wave = t >> 6, lane = t & 63;
  const int sub = lane >> 4, cg = lane & 15;

  u64 e0 = p0[b * 16];
  #pragma unroll
  for (int i = 1; i < 16; ++i) e0 = umin64(e0, p0[b * 16 + i]);
  u64 e1 = p1[b * 4];
  #pragma unroll
  for (int i = 1; i < 4; ++i) e1 = umin64(e1, p1[b * 4 + i]);
  const int a0 = (int)(e0 & 0xffffffffu);
  const int a1 = (int)(e1 & 0xffffffffu);

  qa[t] = Fb[(size_t)a0 * D + t];
  qb[t] = Fb[(size_t)a1 * D + t];
  float dsum = 0.f;
  for (int k = t; k < K; k += 256) {
    const size_t o = (size_t)b * K + k;
    const float d = Dgp[o] + Dgp[(size_t)128 * K + o]
                  + Dgp[(size_t)2 * 128 * K + o] + Dgp[(size_t)3 * 128 * K + o];
    dinv_s[k] = 1.0f / sqrtf(d + EPSF);
    sqd_s[k] = sqrtf(d);
    dsum += d;
  }
  #pragma unroll
  for (int off = 32; off >= 1; off >>= 1) dsum += __shfl_down(dsum, off, 64);
  if (lane == 0) red[wave] = dsum;
  __syncthreads();
  const float vn = 1.0f / sqrtf(red[0] + red[1] + red[2] + red[3]);
  const float s0 = vn * sqd_s[a0], s1 = vn * sqd_s[a1];   // v[a0], v[a1]
  const float dia0 = dinv_s[a0], dia1 = dinv_s[a1];
  const float c99 = ALPHA / (1.0f - ALPHA);

  float2* ob = (float2*)(out + (size_t)b * K * 2);

  #pragma unroll
  for (int pass = 0; pass < 4; ++pass) {
    const int r = r0 + pass * 16 + wave * 4 + sub;
    const __bf16* fr = Fbb + (size_t)r * D;
    float pa = 0.f, pb = 0.f;
    #pragma unroll
    for (int q = 0; q < 2; ++q) {
      const int c = q * 128 + cg * 8;
      const uint4 wv = *(const uint4*)(fr + c);
      const float4 a0v = *(const float4*)(qa + c);
      const float4 a1v = *(const float4*)(qa + c + 4);
      const float4 b0v = *(const float4*)(qb + c);
      const float4 b1v = *(const float4*)(qb + c + 4);
      const float w0 = __uint_as_float(wv.x << 16);
      const float w1 = __uint_as_float(wv.x & 0xffff0000u);
      const float w2 = __uint_as_float(wv.y << 16);
      const float w3 = __uint_as_float(wv.y & 0xffff0000u);
      const float w4 = __uint_as_float(wv.z << 16);
      const float w5 = __uint_as_float(wv.z & 0xffff0000u);
      const float w6 = __uint_as_float(wv.w << 16);
      const float w7 = __uint_as_float(wv.w & 0xffff0000u);
      pa += w0*a0v.x + w1*a0v.y + w2*a0v.z + w3*a0v.w
          + w4*a1v.x + w5*a1v.y + w6*a1v.z + w7*a1v.w;
      pb += w0*b0v.x + w1*b0v.y + w2*b0v.z + w3*b0v.w
          + w4*b1v.x + w5*b1v.y + w6*b1v.z + w7*b1v.w;
    }
    pa += __shfl_xor(pa, 1, 64); pa += __shfl_xor(pa, 2, 64);
    pa += __shfl_xor(pa, 4, 64); pa += __shfl_xor(pa, 8, 64);
    pb += __shfl_xor(pb, 1, 64); pb += __shfl_xor(pb, 2, 64);
    pb += __shfl_xor(pb, 4, 64); pb += __shfl_xor(pb, 8, 64);
    if (cg == 0) {
      const float q0 = ((r == a0) ? 0.f : __expf(pa)) * dia0;
      const float q1 = ((r == a1) ? 0.f : __expf(pb)) * dia1;
      const float di = dinv_s[r];
      const float vr = vn * sqd_s[r];                      // v[r]
      const float w0n = ALPHA * (di * q0 - vr * s0);
      const float w1n = ALPHA * (di * q1 - vr * s1);
      float2 o;
      o.x = ((r == a0) ? 1.f : 0.f) + w0n + c99 * s0 * vr;
      o.y = ((r == a1) ? 1.f : 0.f) + w1n + c99 * s1 * vr;
      ob[r] = o;
    }
  }
}

// ==========================================================================
extern "C" void kernel_launch(void* const* d_in, const int* in_sizes, int n_in,
                              void* d_out, int out_size, void* d_ws, size_t ws_size,
                              hipStream_t stream) {
  const float* F = (const float*)d_in[0];   // [B,K,D]
  const float* Q = (const float*)d_in[1];   // [B,D]
  float* out = (float*)d_out;               // [B,K,2]
  const int B = in_sizes[1] / D;            // 128

  __bf16* Fbf = (__bf16*)d_ws;                           // B*K*D bf16 (33.5 MB)
  float* Dgp  = (float*)(Fbf + (size_t)B * K * D);       // 4*B*K (partial degrees)
  float* simb = Dgp + (size_t)4 * B * K;                 // B*K
  u64*   p0   = (u64*)(simb + (size_t)B * K);            // B*16
  u64*   p1   = p0 + (size_t)B * 16;                     // B*4

  sim1_kernel<<<dim3(16, B), 256, 0, stream>>>(F, Q, Fbf, simb, p0);
  fused_kernel<<<1792, 512, 0, stream>>>(F, Fbf, simb, p0, p1, Dgp);
  final_kernel<<<dim3(8, B), 256, 0, stream>>>(F, Fbf, Dgp, p0, p1, out);
}